// Round 8
// baseline (889.073 us; speedup 1.0000x reference)
//
#include <hip/hip_runtime.h>
#include <cstdint>
#include <cstddef>

#ifndef M_PI
#define M_PI 3.14159265358979323846
#endif

#define SRATE   16000
#define HOP     256
#define NFFT    2048
#define NBINS   1025
#define NMELS   80
#define BATCH   16
#define TLEN    131072
#define NF      513                 // frames
#define LOLA    133120              // NFFT + HOP*(NF-1)
#define FRAMEL  512
#define MINP    32
#define NLAGS   224                 // lags 32..255
#define NELEM   (BATCH*NBINS*NF)    // 8,413,200
#define MLPR    4                   // rows per k_mlp block (8208 = 4*2052)
#define DF      7.8125f             // (SRATE/2)/(NBINS-1), exact in f32

#define PADF(i) ((i) + 3*((i) >> 5))  // f32-LDS padding: all FFT patterns <=2-way

// ---------------- threefry2x32 (bit-exact vs jax) ----------------
__host__ __device__ inline void threefry2x32(uint32_t k0, uint32_t k1,
                                             uint32_t x0, uint32_t x1,
                                             uint32_t& o0, uint32_t& o1) {
  uint32_t ks0 = k0, ks1 = k1, ks2 = k0 ^ k1 ^ 0x1BD11BDAu;
  uint32_t ks[3] = {ks0, ks1, ks2};
  const uint32_t rot[2][4] = {{13u,15u,26u,6u},{17u,29u,16u,24u}};
  x0 += ks0; x1 += ks1;
#pragma unroll
  for (int i = 0; i < 5; ++i) {
#pragma unroll
    for (int r = 0; r < 4; ++r) {
      uint32_t rr = rot[i & 1][r];
      x0 += x1;
      x1 = (x1 << rr) | (x1 >> (32u - rr));
      x1 ^= x0;
    }
    x0 += ks[(i + 1) % 3];
    x1 += ks[(i + 2) % 3] + (uint32_t)(i + 1);
  }
  o0 = x0; o1 = x1;
}

__device__ inline float bits_to_uniform(uint32_t b) {
  uint32_t fb = (b >> 9) | 0x3f800000u;
  return __uint_as_float(fb) - 1.0f;    // [0,1), f32 like jax
}

// ---------------- register-blocked 1024-pt complex FFT (f32) ----------------
// 128 lanes (t = 0..127) x 8 complex f32. DIT radix-2; caller gathers bit-reversed.
// After P4, register m of lane t holds bin g = t + 128*m (natural order).
// t is a PARAMETER so dual-frame 256-thread blocks can run two independent
// FFTs (separate sre/sim arrays) in lockstep; __syncthreads spans both halves
// (correctness-neutral, occupancy-positive).
#define BF(e,o,WR,WI) do{ float vr=Xr[o]*(WR)-Xi[o]*(WI); \
  float vi=Xr[o]*(WI)+Xi[o]*(WR); float ur=Xr[e],ui=Xi[e]; \
  Xr[e]=ur+vr; Xi[e]=ui+vi; Xr[o]=ur-vr; Xi[o]=ui-vi; }while(0)

__device__ __forceinline__ void fft1024(int t, float (&Xr)[8], float (&Xi)[8],
    float* __restrict__ sre, float* __restrict__ sim,
    const float* __restrict__ twr, const float* __restrict__ twi, float sgn)
{
  const float C7 = 0.70710678118654752440f;
  // ---- P1: g = 8t+m, h=1,2,4
  BF(0,1,1.0f,0.0f); BF(2,3,1.0f,0.0f); BF(4,5,1.0f,0.0f); BF(6,7,1.0f,0.0f);
  BF(0,2,1.0f,0.0f); BF(1,3,0.0f,sgn); BF(4,6,1.0f,0.0f); BF(5,7,0.0f,sgn);
  BF(0,4,1.0f,0.0f); BF(1,5,C7,sgn*C7); BF(2,6,0.0f,sgn); BF(3,7,-C7,sgn*C7);
  __syncthreads();
#pragma unroll
  for (int m = 0; m < 8; ++m) { int p = PADF(8*t + m); sre[p] = Xr[m]; sim[p] = Xi[m]; }
  __syncthreads();
  // ---- P2: g = f0 + 8m + 64f1, h=8,16,32
  {
    int f0 = t & 7, f1 = t >> 3;
#pragma unroll
    for (int m = 0; m < 8; ++m) { int p = PADF(f0 + 8*m + 64*f1); Xr[m] = sre[p]; Xi[m] = sim[p]; }
    int x = 128*f0; float wr = twr[x], wi = sgn*twi[x];
    BF(0,1,wr,wi); BF(2,3,wr,wi); BF(4,5,wr,wi); BF(6,7,wr,wi);
    x = 64*f0;      float ar = twr[x], ai = sgn*twi[x];
    x = 64*(f0+8);  float br = twr[x], bi = sgn*twi[x];
    BF(0,2,ar,ai); BF(1,3,br,bi); BF(4,6,ar,ai); BF(5,7,br,bi);
#pragma unroll
    for (int mm = 0; mm < 4; ++mm) {
      x = 32*(f0 + 8*mm); float cr = twr[x], ci = sgn*twi[x];
      BF(mm, mm+4, cr, ci);
    }
#pragma unroll
    for (int m = 0; m < 8; ++m) { int p = PADF(f0 + 8*m + 64*f1); sre[p] = Xr[m]; sim[p] = Xi[m]; }
  }
  __syncthreads();
  // ---- P3: g = f0 + 64m + 512f1, h=64,128,256
  {
    int f0 = t & 63, f1 = t >> 6;
#pragma unroll
    for (int m = 0; m < 8; ++m) { int p = PADF(f0 + 64*m + 512*f1); Xr[m] = sre[p]; Xi[m] = sim[p]; }
    int x = 16*f0; float wr = twr[x], wi = sgn*twi[x];
    BF(0,1,wr,wi); BF(2,3,wr,wi); BF(4,5,wr,wi); BF(6,7,wr,wi);
    x = 8*f0;       float ar = twr[x], ai = sgn*twi[x];
    x = 8*(f0+64);  float br = twr[x], bi = sgn*twi[x];
    BF(0,2,ar,ai); BF(1,3,br,bi); BF(4,6,ar,ai); BF(5,7,br,bi);
#pragma unroll
    for (int mm = 0; mm < 4; ++mm) {
      x = 4*(f0 + 64*mm); float cr = twr[x], ci = sgn*twi[x];
      BF(mm, mm+4, cr, ci);
    }
#pragma unroll
    for (int m = 0; m < 8; ++m) { int p = PADF(f0 + 64*m + 512*f1); sre[p] = Xr[m]; sim[p] = Xi[m]; }
  }
  __syncthreads();
  // ---- P4: g = t + 128m, h=512
  {
#pragma unroll
    for (int m = 0; m < 8; ++m) { int p = PADF(t + 128*m); Xr[m] = sre[p]; Xi[m] = sim[p]; }
#pragma unroll
    for (int mm = 0; mm < 4; ++mm) {
      int x = 2*t + 256*mm; float cr = twr[x], ci = sgn*twi[x];
      BF(mm, mm+4, cr, ci);
    }
  }
}

// forward r2c epilogue (f32): registers hold Z[g=t+128m] of packed z[n]=x[2n]+ix[2n+1].
__device__ __forceinline__ void r2c_combine(int t, float (&Xr)[8], float (&Xi)[8],
    float* __restrict__ sre, float* __restrict__ sim,
    const float* __restrict__ twr, const float* __restrict__ twi,
    float& x1024r)
{
  __syncthreads();
#pragma unroll
  for (int m = 0; m < 8; ++m) { int p = PADF(t + 128*m); sre[p] = Xr[m]; sim[p] = Xi[m]; }
  __syncthreads();
  if (t == 0) x1024r = Xr[0] - Xi[0];
#pragma unroll
  for (int m = 0; m < 8; ++m) {
    int k  = t + 128*m;
    int km = PADF((1024 - k) & 1023);
    float zmr = sre[km], zmi = sim[km];
    float Er  = 0.5f*(Xr[m] + zmr), Ei  = 0.5f*(Xi[m] - zmi);
    float Odr = 0.5f*(Xr[m] - zmr), Odi = 0.5f*(Xi[m] + zmi);
    float Or  = Odi, Oi = -Odr;          // O = -i*(Z-conj(Zm))/2
    float wr  = twr[k], wi = -twi[k];    // W = e^{-i*2pi*k/2048}
    Xr[m] = Er + (wr*Or - wi*Oi);
    Xi[m] = Ei + (wr*Oi + wi*Or);
  }
}

// mel -> linear interp for one bin k from LDS f32 melrow (f32 math; src never
// within 1/410 of an integer so f32 rounding cannot flip i0)
__device__ inline float lin_interp_s(const float* __restrict__ melsh, int k) {
  float src = ((float)k + 0.5f) * ((float)NMELS / (float)NBINS) - 0.5f;
  src = src < 0.0f ? 0.0f : src;
  int i0 = (int)src; if (i0 > NMELS - 1) i0 = NMELS - 1;
  int i1 = i0 + 1 > NMELS - 1 ? NMELS - 1 : i0 + 1;
  float w = src - (float)i0;
  return (1.0f - w) * melsh[i0] + w * melsh[i1];
}

// ---------------- init A: paired window, win^2, f32 twiddles, f_pts, mel ranges ----------------
__global__ __launch_bounds__(256) void k_init_a(float2* __restrict__ winp,
                                                double* __restrict__ win2,
                                                float* __restrict__ twrf, float* __restrict__ twif,
                                                float* __restrict__ fptsf,
                                                int2* __restrict__ melrange) {
  int i = blockIdx.x * 256 + threadIdx.x;
  if (i < NFFT) {
    double w = 0.5 - 0.5 * cos(2.0 * M_PI * (double)i / (double)NFFT);
    win2[i] = w * w;
  }
  if (i < 1024) {
    double w0 = 0.5 - 0.5 * cos(2.0 * M_PI * (double)(2*i)   / (double)NFFT);
    double w1 = 0.5 - 0.5 * cos(2.0 * M_PI * (double)(2*i+1) / (double)NFFT);
    winp[i] = make_float2((float)w0, (float)w1);
    double th = 2.0 * M_PI * (double)i / (double)NFFT;
    twrf[i] = (float)cos(th); twif[i] = (float)sin(th);
  }
  if (i < NMELS + 2) {                   // f_pts[82], same formula/order as reference
    double m_max = 2595.0 * log10(1.0 + (SRATE / 2.0) / 700.0);
    fptsf[i] = (float)(700.0 * (pow(10.0, ((double)i * m_max / (double)(NMELS + 1)) / 2595.0) - 1.0));
  }
  if (i < NMELS) {                       // per-mel positive-weight bin range [lo,hi) — analytic
    double m_max = 2595.0 * log10(1.0 + (SRATE / 2.0) / 700.0);
    double fp0 = 700.0 * (pow(10.0, ((double)i       * m_max / (double)(NMELS + 1)) / 2595.0) - 1.0);
    double fp1 = 700.0 * (pow(10.0, ((double)(i + 1) * m_max / (double)(NMELS + 1)) / 2595.0) - 1.0);
    double fp2 = 700.0 * (pow(10.0, ((double)(i + 2) * m_max / (double)(NMELS + 1)) / 2595.0) - 1.0);
    int lo = (int)floor(fp0 / 7.8125) + 1;
    int hi = (int)ceil (fp2 / 7.8125);
    if (lo < 0) lo = 0; if (lo > NBINS) lo = NBINS;
    if (hi < 0) hi = 0; if (hi > NBINS) hi = NBINS;
    #define WGT(k) fmin(((double)(k)*7.8125 - fp0)/(fp1 - fp0), (fp2 - (double)(k)*7.8125)/(fp2 - fp1))
    while (lo > 0 && WGT(lo - 1) > 0.0) --lo;
    while (lo < hi && WGT(lo) <= 0.0) ++lo;
    while (hi < NBINS && WGT(hi) > 0.0) ++hi;
    while (hi > lo && WGT(hi - 1) <= 0.0) --hi;
    #undef WGT
    melrange[i] = make_int2(lo, hi);
  }
}

// ---------------- init B: envelope reciprocal ----------------
__global__ __launch_bounds__(256) void k_init_b(const double* __restrict__ win2,
                                                float* __restrict__ envif) {
  int i = blockIdx.x * 256 + threadIdx.x;
  if (i < LOLA) {
    int lo = i - (NFFT - 1);
    int fmin = lo <= 0 ? 0 : (lo + HOP - 1) / HOP;
    int fmax = i / HOP; if (fmax > NF - 1) fmax = NF - 1;
    double s = 0.0;
    for (int f = fmin; f <= fmax; ++f) s += win2[i - HOP * f];
    envif[i] = (float)(1.0 / (s > 1e-11 ? s : 1.0));
  }
}

// ---------------- STFT (real-packed, f32) + mel GATHER (no atomics) ----------------
__global__ __launch_bounds__(128) void k_stft_mel(const float* __restrict__ x,
                                                  const float2* __restrict__ winp,
                                                  const float* __restrict__ twrf, const float* __restrict__ twif,
                                                  const float* __restrict__ fptsf, const int2* __restrict__ melrange,
                                                  float* __restrict__ mel) {
  __shared__ float sre[1160], sim[1160];
  __shared__ float fsh[NMELS + 2];
  __shared__ int2  rsh[NMELS];
  int b = blockIdx.x / NF, tf = blockIdx.x % NF;
  int t = threadIdx.x;
  const float* xb = x + (size_t)b * TLEN;
  if (t < NMELS + 2) fsh[t] = fptsf[t];
  if (t < NMELS)     rsh[t] = melrange[t];
  if (tf >= 4 && tf <= 508) {            // interior: natural float2 loads
    const float2* xb2 = (const float2*)xb;
#pragma unroll
    for (int s = 0; s < 8; ++s) {
      int n = t + 128 * s;
      float2 v = xb2[128 * tf + n - 512];
      float2 w = winp[n];
      sre[PADF(n)] = v.x * w.x;
      sim[PADF(n)] = v.y * w.y;
    }
  } else {
#pragma unroll
    for (int s = 0; s < 8; ++s) {        // boundary: reflect scalar path
      int n = t + 128 * s;
      int j0 = HOP * tf + 2 * n - (NFFT / 2);
      int m0 = j0 < 0 ? -j0 : (j0 >= TLEN ? 2 * TLEN - 2 - j0 : j0);
      int j1 = j0 + 1;
      int m1 = j1 < 0 ? -j1 : (j1 >= TLEN ? 2 * TLEN - 2 - j1 : j1);
      float2 w = winp[n];
      sre[PADF(n)] = xb[m0] * w.x;
      sim[PADF(n)] = xb[m1] * w.y;
    }
  }
  __syncthreads();
  float Xr[8], Xi[8];
  int rt = (int)(__brev((unsigned)t) >> 25);
  const int r3[8] = {0,4,2,6,1,5,3,7};
#pragma unroll
  for (int m = 0; m < 8; ++m) {
    int p = PADF(rt + 128 * r3[m]);
    Xr[m] = sre[p]; Xi[m] = sim[p];
  }
  fft1024(t, Xr, Xi, sre, sim, twrf, twif, -1.0f);
  float x1024r = 0.0f;
  r2c_combine(t, Xr, Xi, sre, sim, twrf, twif, x1024r);
  __syncthreads();
#pragma unroll
  for (int m = 0; m < 8; ++m) {
    int k = t + 128 * m;
    sre[k] = sqrtf(Xr[m]*Xr[m] + Xi[m]*Xi[m]);
  }
  if (t == 0) sre[1024] = fabsf(x1024r);
  __syncthreads();
  if (t < NMELS) {                        // gather: one mel per thread
    float fp0 = fsh[t], fp1 = fsh[t + 1], fp2 = fsh[t + 2];
    float id0 = 1.0f / (fp1 - fp0), id1 = 1.0f / (fp2 - fp1);
    int2 r = rsh[t];
    float acc = 0.0f;
    for (int k = r.x; k < r.y; ++k) {
      float freq = (float)k * DF;
      float w = fminf((freq - fp0) * id0, (fp2 - freq) * id1);
      acc += sre[k] * fmaxf(w, 0.0f);
    }
    mel[(size_t)blockIdx.x * NMELS + t] = acc;
  }
}

// ---------------- iSTFT #0, DUAL-FRAME: threefry angles fused in ----------------
// 256 threads = 2 frames/block (tid<128 -> row 2*bid, else 2*bid+1), separate LDS
// halves; barriers lockstep both frames (harmless). Per-thread code identical to
// the 128-thread version -> values bit-identical. Raises waves/block 2->4 to beat
// the ~5-6 resident-blocks/CU plateau observed across all 128-thread kernels.
__global__ __launch_bounds__(256) void k_istft0(const float* __restrict__ mel,
                                                const float2* __restrict__ winp,
                                                const float* __restrict__ twrf, const float* __restrict__ twif,
                                                float2* __restrict__ fr2,
                                                uint32_t kr0, uint32_t kr1,
                                                uint32_t ki0, uint32_t ki1) {
  __shared__ float sreb[2][1160], simb[2][1160];
  __shared__ float melshb[2][NMELS];
  int half = threadIdx.x >> 7, t = threadIdx.x & 127;
  float* sre = sreb[half];  float* sim = simb[half];  float* melsh = melshb[half];
  size_t row = (size_t)blockIdx.x * 2 + half;
  int b = (int)(row / NF), tf = (int)(row % NF);
  if (t < NMELS) melsh[t] = mel[row * NMELS + t];
  __syncthreads();
  for (int s = 0; s < 9; ++s) {          // stage X[k] = spec*angle; imag 0 at DC/Nyquist
    int k = t + 128 * s;
    if (k < NBINS) {
      uint32_t j = ((uint32_t)b * (uint32_t)NBINS + (uint32_t)k) * (uint32_t)NF + (uint32_t)tf;
      uint32_t a0, a1, b0, b1;
      threefry2x32(kr0, kr1, 0u, j, a0, a1);   // real part bits
      threefry2x32(ki0, ki1, 0u, j, b0, b1);   // imag part bits
      float ux = bits_to_uniform(a0 ^ a1);
      float uy = bits_to_uniform(b0 ^ b1);
      float sv = lin_interp_s(melsh, k);
      sre[PADF(k)] = sv * ux;
      sim[PADF(k)] = (k == 0 || k == 1024) ? 0.0f : sv * uy;
    }
  }
  __syncthreads();
  float Xr[8], Xi[8];
  int rt = (int)(__brev((unsigned)t) >> 25);
  const int r3[8] = {0,4,2,6,1,5,3,7};
#pragma unroll
  for (int m = 0; m < 8; ++m) {          // Z[n] = E + i*O, gathered bit-reversed
    int n  = rt + 128 * r3[m];
    int p  = PADF(n), q = PADF(1024 - n);
    float Er = 0.5f*(sre[p] + sre[q]), Ei = 0.5f*(sim[p] - sim[q]);
    float Fr = 0.5f*(sre[p] - sre[q]), Fi = 0.5f*(sim[p] + sim[q]);
    float wr = twrf[n], wi = twif[n];    // e^{+i*2pi*n/2048}
    float Or = wr*Fr - wi*Fi, Oi = wr*Fi + wi*Fr;
    Xr[m] = Er - Oi;
    Xi[m] = Ei + Or;
  }
  fft1024(t, Xr, Xi, sre, sim, twrf, twif, +1.0f);
  float2* frrow = fr2 + row * 1024;
  const float invM = 1.0f / 1024.0f;
#pragma unroll
  for (int m = 0; m < 8; ++m) {          // z[g]: x[2g]=Re, x[2g+1]=Im; coalesced float2
    int g = t + 128 * m;
    float2 w = winp[g];
    frrow[g] = make_float2(Xr[m] * invM * w.x,
                           Xi[m] * invM * w.y);
  }
}

// ---------------- FUSED + DUAL-FRAME: STFT(y) + GL angle update + iSTFT -> fr ----------------
// Same fusion as round 7 (A never materialized), now 2 frames per 256-thread block.
__global__ __launch_bounds__(256) void k_gl_istft(const float* __restrict__ y,
                                                  const float* __restrict__ mel,
                                                  const float2* __restrict__ winp,
                                                  const float* __restrict__ twrf, const float* __restrict__ twif,
                                                  float2* __restrict__ P, float2* __restrict__ fr2,
                                                  float momf, int writeP) {
  __shared__ float sreb[2][1160], simb[2][1160];
  __shared__ float melshb[2][NMELS];
  int half = threadIdx.x >> 7, t = threadIdx.x & 127;
  float* sre = sreb[half];  float* sim = simb[half];  float* melsh = melshb[half];
  size_t row = (size_t)blockIdx.x * 2 + half;
  int b = (int)(row / NF), tf = (int)(row % NF);
  float2* Prow = P + row * NBINS;
  const bool readP = (momf != 0.0f);
  float2 pfr[8];
  float2 pny = make_float2(0.0f, 0.0f);
  if (readP) {                           // prefetch momentum row: hides under forward FFT
#pragma unroll
    for (int m = 0; m < 8; ++m) pfr[m] = Prow[t + 128 * m];
    if (t == 0) pny = Prow[1024];
  } else {
#pragma unroll
    for (int m = 0; m < 8; ++m) pfr[m] = make_float2(0.0f, 0.0f);
  }
  if (t < NMELS) melsh[t] = mel[row * NMELS + t];
  const float* yb = y + (size_t)b * LOLA;
  if (tf >= 4 && tf <= 508) {            // interior: y index = 256*tf + 2n -> float2
    const float2* yb2 = (const float2*)yb;
#pragma unroll
    for (int s = 0; s < 8; ++s) {
      int n = t + 128 * s;
      float2 v = yb2[128 * tf + n];
      float2 w = winp[n];
      sre[PADF(n)] = v.x * w.x;
      sim[PADF(n)] = v.y * w.y;
    }
  } else {
#pragma unroll
    for (int s = 0; s < 8; ++s) {
      int n = t + 128 * s;
      int j0 = HOP * tf + 2 * n - (NFFT / 2);
      int m0 = j0 < 0 ? -j0 : (j0 >= TLEN ? 2 * TLEN - 2 - j0 : j0);
      int j1 = j0 + 1;
      int m1 = j1 < 0 ? -j1 : (j1 >= TLEN ? 2 * TLEN - 2 - j1 : j1);
      float2 w = winp[n];
      sre[PADF(n)] = yb[NFFT/2 + m0] * w.x;
      sim[PADF(n)] = yb[NFFT/2 + m1] * w.y;
    }
  }
  __syncthreads();
  float Xr[8], Xi[8];
  int rt = (int)(__brev((unsigned)t) >> 25);
  const int r3[8] = {0,4,2,6,1,5,3,7};
#pragma unroll
  for (int m = 0; m < 8; ++m) {
    int p = PADF(rt + 128 * r3[m]);
    Xr[m] = sre[p]; Xi[m] = sim[p];
  }
  fft1024(t, Xr, Xi, sre, sim, twrf, twif, -1.0f);
  float x1024r = 0.0f;
  r2c_combine(t, Xr, Xi, sre, sim, twrf, twif, x1024r);   // Xr/Xi = rebuilt[k=t+128m]
  __syncthreads();                       // all r2c reads done before spec overwrite
#pragma unroll
  for (int m = 0; m < 8; ++m) {          // angle + momentum (f32, identical to split)
    int k = t + 128 * m;
    float ar = Xr[m] - momf * pfr[m].x;
    float ai = Xi[m] - momf * pfr[m].y;
    float mg = sqrtf(ar * ar + ai * ai) + 1e-16f;
    float inv = 1.0f / mg;
    if (writeP) Prow[k] = make_float2(Xr[m], Xi[m]);
    float sv = lin_interp_s(melsh, k);
    sre[PADF(k)] = sv * (ar * inv);
    sim[PADF(k)] = (k == 0) ? 0.0f : sv * (ai * inv);   // irfft drops DC imag
  }
  if (t == 0) {                          // Nyquist bin (imag dropped by irfft)
    float ar = x1024r - momf * pny.x;
    float ai = -momf * pny.y;
    float mg = sqrtf(ar * ar + ai * ai) + 1e-16f;
    float inv = 1.0f / mg;
    if (writeP) Prow[1024] = make_float2(x1024r, 0.0f);
    float sv = lin_interp_s(melsh, 1024);
    sre[PADF(1024)] = sv * (ar * inv);
    sim[PADF(1024)] = 0.0f;
    (void)ai;
  }
  __syncthreads();
#pragma unroll
  for (int m = 0; m < 8; ++m) {          // Z[n] = E + i*O, gathered bit-reversed
    int n  = rt + 128 * r3[m];
    int p  = PADF(n), q = PADF(1024 - n);
    float Er = 0.5f*(sre[p] + sre[q]), Ei = 0.5f*(sim[p] - sim[q]);
    float Fr = 0.5f*(sre[p] - sre[q]), Fi = 0.5f*(sim[p] + sim[q]);
    float wr = twrf[n], wi = twif[n];    // e^{+i*2pi*n/2048}
    float Or = wr*Fr - wi*Fi, Oi = wr*Fi + wi*Fr;
    Xr[m] = Er - Oi;
    Xi[m] = Ei + Or;
  }
  fft1024(t, Xr, Xi, sre, sim, twrf, twif, +1.0f);
  float2* frrow = fr2 + row * 1024;
  const float invM = 1.0f / 1024.0f;
#pragma unroll
  for (int m = 0; m < 8; ++m) {          // z[g]: x[2g]=Re, x[2g+1]=Im; coalesced float2
    int g = t + 128 * m;
    float2 w = winp[g];
    frrow[g] = make_float2(Xr[m] * invM * w.x,
                           Xi[m] * invM * w.y);
  }
}

// ---------------- OLA gather + normalize, 4 samples/thread ----------------
__global__ __launch_bounds__(256) void k_ola(const float* __restrict__ fr,
                                             const float* __restrict__ envif,
                                             float* __restrict__ y, float* __restrict__ out) {
  size_t idx = (size_t)blockIdx.x * 256 + threadIdx.x;
  const size_t QROW = LOLA / 4;           // 33280 quads per batch row
  if (idx >= (size_t)BATCH * QROW) return;
  int b = (int)(idx / QROW);
  int i0 = 4 * (int)(idx % QROW);
  const float* frb = fr + (size_t)b * NF * NFFT;
  int lo0 = i0 - (NFFT - 1);
  int fm0 = lo0 <= 0 ? 0 : (lo0 + HOP - 1) / HOP;
  int fx0 = i0 / HOP; if (fx0 > NF - 1) fx0 = NF - 1;
  int i3 = i0 + 3;
  int lo3 = i3 - (NFFT - 1);
  int fm3 = lo3 <= 0 ? 0 : (lo3 + HOP - 1) / HOP;
  int fx3 = i3 / HOP; if (fx3 > NF - 1) fx3 = NF - 1;
  float4 v;
  if (fm0 == fm3 && fx0 == fx3) {         // uniform range: float4 fast path
    float4 s = make_float4(0.f, 0.f, 0.f, 0.f);
    for (int f = fm0; f <= fx0; ++f) {
      const float4 a = *(const float4*)(frb + (size_t)f * NFFT + (i0 - HOP * f));
      s.x += a.x; s.y += a.y; s.z += a.z; s.w += a.w;
    }
    const float4 e = *(const float4*)(envif + i0);
    v = make_float4(s.x * e.x, s.y * e.y, s.z * e.z, s.w * e.w);
  } else {                                // boundary quad: per-element
    float vv[4];
#pragma unroll
    for (int u = 0; u < 4; ++u) {
      int i = i0 + u;
      int lo = i - (NFFT - 1);
      int fmin = lo <= 0 ? 0 : (lo + HOP - 1) / HOP;
      int fmax = i / HOP; if (fmax > NF - 1) fmax = NF - 1;
      float s = 0.0f;
      for (int f = fmin; f <= fmax; ++f)
        s += frb[(size_t)f * NFFT + (i - HOP * f)];
      vv[u] = s * envif[i];
    }
    v = make_float4(vv[0], vv[1], vv[2], vv[3]);
  }
  if (out) {
    int j0 = i0 - NFFT / 2;               // 1024-aligned shift: j0 % 4 == 0
    if (j0 >= 0 && j0 + 3 < TLEN) {
      *(float4*)(out + (size_t)b * TLEN + j0) = v;
    } else {
      const float vv[4] = {v.x, v.y, v.z, v.w};
#pragma unroll
      for (int u = 0; u < 4; ++u) {
        int j = j0 + u;
        if (j >= 0 && j < TLEN) out[(size_t)b * TLEN + j] = vv[u];
      }
    }
  } else {
    *(float4*)(y + (size_t)b * LOLA + i0) = v;
  }
}

// ---------------- f0 + loudness (constant-sum lag quads, 8 n-phases) ----------------
// Round-3-proven version (72.4us): f64 quads, xd[528]. LDS padding experiments
// (rounds 4-6) all regressed — keeping the measured-best code.
__global__ __launch_bounds__(256) void k_feats(const float* __restrict__ x, double* __restrict__ feats) {
  __shared__ __align__(16) double xd[528];   // frame in f64; [512..527] zero pad
  __shared__ double pacc[8][224];            // per-phase lag partials
  __shared__ double red[256];                // loudness reduce
  __shared__ double cval[256];
  __shared__ int    cidx[256];
  int b = blockIdx.x / NF, tf = blockIdx.x % NF;
  const float* xb = x + (size_t)b * TLEN;
  int tid = threadIdx.x;
  for (int n = tid; n < FRAMEL; n += 256) {
    int j = HOP * tf + n - (FRAMEL / 2);
    int m = j < 0 ? -j : (j >= TLEN ? 2 * TLEN - 2 - j : j);
    xd[n] = (double)xb[m];
  }
  if (tid < 16) xd[FRAMEL + tid] = 0.0;
  __syncthreads();
  // loudness sum of squares (f64 accum of exact f32 values)
  double ss = 0.0;
  for (int n = tid; n < FRAMEL; n += 256) { double v = xd[n]; ss += v * v; }
  red[tid] = ss;
  __syncthreads();
  for (int w = 128; w > 0; w >>= 1) {
    if (tid < w) red[tid] += red[tid + w];
    __syncthreads();
  }
  double sumsq = red[0];
  // autocorrelation
  int g = tid & 31, ph = tid >> 5;
  double acc[8];
#pragma unroll
  for (int d = 0; d < 8; ++d) acc[d] = 0.0;
  if (g < 28) {
    const double2* d2 = (const double2*)xd;
    const int LA = 32 + 4 * g;            // quad A: lags LA..LA+3 (32..143)
    const int LB = 252 - 4 * g;           // quad B: lags LB..LB+3 (144..255)
    for (int n0 = 8 * ph; n0 < 512 - LA; n0 += 64) {
      int h = n0 >> 1, hb = (n0 + LA) >> 1;   // both even offsets -> aligned
      double2 a0 = d2[h],      a1 = d2[h + 1],  a2 = d2[h + 2],  a3 = d2[h + 3];
      double2 b0 = d2[hb],     b1 = d2[hb + 1], b2 = d2[hb + 2],
              b3 = d2[hb + 3], b4 = d2[hb + 4], b5 = d2[hb + 5];
      double aa[8]  = {a0.x,a0.y,a1.x,a1.y,a2.x,a2.y,a3.x,a3.y};
      double bb[12] = {b0.x,b0.y,b1.x,b1.y,b2.x,b2.y,b3.x,b3.y,b4.x,b4.y,b5.x,b5.y};
#pragma unroll
      for (int d = 0; d < 4; ++d)
#pragma unroll
        for (int jj = 0; jj < 8; ++jj)
          acc[d] += aa[jj] * bb[jj + d];      // static idx after unroll -> regs
    }
    for (int n0 = 8 * ph; n0 < 512 - LB; n0 += 64) {
      int h = n0 >> 1, hb = (n0 + LB) >> 1;
      double2 a0 = d2[h],      a1 = d2[h + 1],  a2 = d2[h + 2],  a3 = d2[h + 3];
      double2 b0 = d2[hb],     b1 = d2[hb + 1], b2 = d2[hb + 2],
              b3 = d2[hb + 3], b4 = d2[hb + 4], b5 = d2[hb + 5];
      double aa[8]  = {a0.x,a0.y,a1.x,a1.y,a2.x,a2.y,a3.x,a3.y};
      double bb[12] = {b0.x,b0.y,b1.x,b1.y,b2.x,b2.y,b3.x,b3.y,b4.x,b4.y,b5.x,b5.y};
#pragma unroll
      for (int d = 0; d < 4; ++d)
#pragma unroll
        for (int jj = 0; jj < 8; ++jj)
          acc[4 + d] += aa[jj] * bb[jj + d];
    }
#pragma unroll
    for (int d = 0; d < 8; ++d) pacc[ph][g * 8 + d] = acc[d];
  }
  __syncthreads();
  if (tid < 224) {                        // deterministic phase combine (ph ascending)
    double tot = 0.0;
#pragma unroll
    for (int p = 0; p < 8; ++p) tot += pacc[p][tid];
    int gg = tid >> 3, dd = tid & 7;
    int lag = dd < 4 ? (32 + 4 * gg + dd) : (252 - 4 * gg + (dd - 4));
    cval[tid] = tot; cidx[tid] = lag;
  } else { cval[tid] = -1e300; cidx[tid] = 1 << 30; }
  __syncthreads();
  for (int w = 128; w > 0; w >>= 1) {     // first-max argmax tree (lag-order tie-break)
    if (tid < w) {
      double vl = cval[tid], vr = cval[tid + w];
      int il = cidx[tid], ir = cidx[tid + w];
      if (vr > vl || (vr == vl && ir < il)) { cval[tid] = vr; cidx[tid] = ir; }
    }
    __syncthreads();
  }
  if (tid == 0) {
    double period = (double)cidx[0];
    double f0 = (double)SRATE / (period + 1e-8);
    f0 = f0 < 50.0 ? 50.0 : (f0 > 500.0 ? 500.0 : f0);
    double mean = sumsq / (double)FRAMEL;
    double loud = 20.0 * log10(sqrt(mean) + 1e-8);
    feats[(size_t)blockIdx.x * 2 + 0] = f0;
    feats[(size_t)blockIdx.x * 2 + 1] = loud;
  }
}

// ---------------- MLP 2->256->256->64 (elu), f32, 4 rows/block ----------------
__global__ __launch_bounds__(256) void k_mlp(const double* __restrict__ feats,
                                             const float* __restrict__ W1, const float* __restrict__ b1,
                                             const float* __restrict__ W2, const float* __restrict__ b2,
                                             const float* __restrict__ W3, const float* __restrict__ b3,
                                             float* __restrict__ out) {
  __shared__ __align__(16) float h1[MLPR][256];
  __shared__ __align__(16) float h2[MLPR][256];
  __shared__ float fsh[MLPR][2];
  int j = threadIdx.x;
  size_t row0 = (size_t)blockIdx.x * MLPR;
  if (j < MLPR * 2) ((float*)fsh)[j] = (float)feats[row0 * 2 + j];
  __syncthreads();
  float w1a = W1[j], w1b = W1[256 + j], bb1 = b1[j];
#pragma unroll
  for (int r = 0; r < MLPR; ++r) {
    float v = fsh[r][0] * w1a + fsh[r][1] * w1b + bb1;
    h1[r][j] = v > 0.0f ? v : expm1f(v);
  }
  __syncthreads();
  float acc[MLPR];
  float bb2 = b2[j];
#pragma unroll
  for (int r = 0; r < MLPR; ++r) acc[r] = bb2;
  const float* w2p = W2 + j;
  for (int i4 = 0; i4 < 64; ++i4) {
    float w0 = w2p[(4 * i4 + 0) * 256];
    float w1 = w2p[(4 * i4 + 1) * 256];
    float w2v = w2p[(4 * i4 + 2) * 256];
    float w3v = w2p[(4 * i4 + 3) * 256];
#pragma unroll
    for (int r = 0; r < MLPR; ++r) {
      float4 hv = ((const float4*)h1[r])[i4];   // broadcast read
      acc[r] += hv.x * w0;
      acc[r] += hv.y * w1;
      acc[r] += hv.z * w2v;
      acc[r] += hv.w * w3v;
    }
  }
#pragma unroll
  for (int r = 0; r < MLPR; ++r) h2[r][j] = acc[r] > 0.0f ? acc[r] : expm1f(acc[r]);
  __syncthreads();
  int o = j & 63, r = j >> 6;             // one row per 64-lane wave (wave-uniform r)
  float oacc = b3[o];
  const float* w3p = W3 + o;
  for (int i4 = 0; i4 < 64; ++i4) {
    float4 hv = ((const float4*)h2[r])[i4];     // broadcast read
    oacc += hv.x * w3p[(4 * i4 + 0) * 64];
    oacc += hv.y * w3p[(4 * i4 + 1) * 64];
    oacc += hv.z * w3p[(4 * i4 + 2) * 64];
    oacc += hv.w * w3p[(4 * i4 + 3) * 64];
  }
  out[(row0 + r) * 64 + o] = oacc;
}

// sentinel: marks "workspace too small" path unambiguously
__global__ void k_sentinel(float* out) { out[0] = 31337.0f; }

// ---------------- host ----------------
extern "C" void kernel_launch(void* const* d_in, const int* in_sizes, int n_in,
                              void* d_out, int out_size, void* d_ws, size_t ws_size,
                              hipStream_t stream) {
  const float* x  = (const float*)d_in[0];
  const float* W1 = (const float*)d_in[1];
  const float* b1 = (const float*)d_in[2];
  const float* W2 = (const float*)d_in[3];
  const float* b2 = (const float*)d_in[4];
  const float* W3 = (const float*)d_in[5];
  const float* b3 = (const float*)d_in[6];
  float* out = (float*)d_out;

  // f64 region
  double* ws = (double*)d_ws;
  size_t o = 0;
  double*  winsq = ws + o; o += NFFT;
  double*  feats = ws + o; o += (size_t)BATCH * NF * 2;
  // f32 region (8B aligned: o doubles consumed)
  float2* winp  = (float2*)(ws + o);                         // 1024 float2
  float*  twrf  = (float*)(winp + 1024);                     // 1024
  float*  twif  = twrf + 1024;                               // 1024
  float*  fptsf = twif + 1024;                               // 84 (pad to even)
  int2*   melrange = (int2*)(fptsf + 84);                    // 80 int2 (8B aligned)
  float*  mel   = (float*)(melrange + NMELS);                // B*NF*80
  float*  fr    = mel + (size_t)BATCH * NF * NMELS;          // B*NF*2048 windowed frames
  float*  y     = fr + (size_t)BATCH * NF * NFFT;            // B*LOLA normalized inv
  float*  envif = y + (size_t)BATCH * LOLA;                  // LOLA
  float2* P     = (float2*)(envif + LOLA);                   // momentum (A is never materialized)
  size_t total_bytes = (size_t)((char*)(P + (size_t)NELEM) - (char*)d_ws);  // ~148 MiB

  if (ws_size < total_bytes) {           // diagnostic path: out[0] = 31337
    k_sentinel<<<1, 1, 0, stream>>>(out);
    return;
  }

  // jax.random.key(42) -> (0,42). Partitionable split: keys[i] = threefry(key, (0, i)).
  uint32_t kr0, kr1, ki0, ki1;
  threefry2x32(0u, 42u, 0u, 0u, kr0, kr1);   // kr = keys[0]
  threefry2x32(0u, 42u, 0u, 1u, ki0, ki1);   // ki = keys[1]

  const int NBLK = BATCH * NF;    // 8208
  const int OLAB = ((size_t)BATCH * (LOLA / 4) + 255) / 256;   // 4 samples/thread
  k_init_a<<<8, 256, 0, stream>>>(winp, winsq, twrf, twif, fptsf, melrange);
  k_init_b<<<(LOLA + 255) / 256, 256, 0, stream>>>(winsq, envif);
  k_stft_mel<<<NBLK, 128, 0, stream>>>(x, winp, twrf, twif, fptsf, melrange, mel);

  const float momf = (float)(0.99 / 1.99);   // reference: f32 multiply of python-f64 scalar
  // istft #0 with fused threefry angles, dual-frame blocks (NBLK = 2*4104 exactly)
  k_istft0<<<NBLK / 2, 256, 0, stream>>>(mel, winp, twrf, twif, (float2*)fr, kr0, kr1, ki0, ki1);
  k_ola<<<OLAB, 256, 0, stream>>>(fr, envif, y, nullptr);
  for (int it = 0; it < 4; ++it) {
    // fused dual-frame: STFT(y) -> GL angle update -> iSTFT -> fr.
    // it==0: mom=0 (P unread). it==3: final angles, P dead -> writeP=0.
    k_gl_istft<<<NBLK / 2, 256, 0, stream>>>(y, mel, winp, twrf, twif, P, (float2*)fr,
                                             it == 0 ? 0.0f : momf, it < 3 ? 1 : 0);
    k_ola<<<OLAB, 256, 0, stream>>>(fr, envif, y, it == 3 ? out : nullptr);
  }

  k_feats<<<NBLK, 256, 0, stream>>>(x, feats);
  k_mlp<<<NBLK / MLPR, 256, 0, stream>>>(feats, W1, b1, W2, b2, W3, b3, out + (size_t)BATCH * TLEN);
}

// Round 9
// 705.752 us; speedup vs baseline: 1.2598x; 1.2598x over previous
//
#include <hip/hip_runtime.h>
#include <cstdint>
#include <cstddef>

#ifndef M_PI
#define M_PI 3.14159265358979323846
#endif

#define SRATE   16000
#define HOP     256
#define NFFT    2048
#define NBINS   1025
#define NMELS   80
#define BATCH   16
#define TLEN    131072
#define NF      513                 // frames
#define LOLA    133120              // NFFT + HOP*(NF-1)
#define FRAMEL  512
#define MINP    32
#define NLAGS   224                 // lags 32..255
#define NELEM   (BATCH*NBINS*NF)    // 8,413,200
#define MLPR    4                   // rows per k_mlp block (8208 = 4*2052)
#define DF      7.8125f             // (SRATE/2)/(NBINS-1), exact in f32

#define PADF(i) ((i) + 3*((i) >> 5))  // f32-LDS padding: all FFT patterns <=2-way

// ---------------- threefry2x32 (bit-exact vs jax) ----------------
__host__ __device__ inline void threefry2x32(uint32_t k0, uint32_t k1,
                                             uint32_t x0, uint32_t x1,
                                             uint32_t& o0, uint32_t& o1) {
  uint32_t ks0 = k0, ks1 = k1, ks2 = k0 ^ k1 ^ 0x1BD11BDAu;
  uint32_t ks[3] = {ks0, ks1, ks2};
  const uint32_t rot[2][4] = {{13u,15u,26u,6u},{17u,29u,16u,24u}};
  x0 += ks0; x1 += ks1;
#pragma unroll
  for (int i = 0; i < 5; ++i) {
#pragma unroll
    for (int r = 0; r < 4; ++r) {
      uint32_t rr = rot[i & 1][r];
      x0 += x1;
      x1 = (x1 << rr) | (x1 >> (32u - rr));
      x1 ^= x0;
    }
    x0 += ks[(i + 1) % 3];
    x1 += ks[(i + 2) % 3] + (uint32_t)(i + 1);
  }
  o0 = x0; o1 = x1;
}

__device__ inline float bits_to_uniform(uint32_t b) {
  uint32_t fb = (b >> 9) | 0x3f800000u;
  return __uint_as_float(fb) - 1.0f;    // [0,1), f32 like jax
}

// ---------------- register-blocked 1024-pt complex FFT (f32) ----------------
// 128 lanes (t = 0..127) x 8 complex f32. DIT radix-2; caller gathers bit-reversed.
// After P4, register m of lane t holds bin g = t + 128*m (natural order).
#define BFX(Xr,Xi,e,o,WR,WI) do{ float vr=Xr[o]*(WR)-Xi[o]*(WI); \
  float vi=Xr[o]*(WI)+Xi[o]*(WR); float ur=Xr[e],ui=Xi[e]; \
  Xr[e]=ur+vr; Xi[e]=ui+vi; Xr[o]=ur-vr; Xi[o]=ui-vi; }while(0)

__device__ __forceinline__ void fft1024(int t, float (&Xr)[8], float (&Xi)[8],
    float* __restrict__ sre, float* __restrict__ sim,
    const float* __restrict__ twr, const float* __restrict__ twi, float sgn)
{
  const float C7 = 0.70710678118654752440f;
  BFX(Xr,Xi,0,1,1.0f,0.0f); BFX(Xr,Xi,2,3,1.0f,0.0f); BFX(Xr,Xi,4,5,1.0f,0.0f); BFX(Xr,Xi,6,7,1.0f,0.0f);
  BFX(Xr,Xi,0,2,1.0f,0.0f); BFX(Xr,Xi,1,3,0.0f,sgn); BFX(Xr,Xi,4,6,1.0f,0.0f); BFX(Xr,Xi,5,7,0.0f,sgn);
  BFX(Xr,Xi,0,4,1.0f,0.0f); BFX(Xr,Xi,1,5,C7,sgn*C7); BFX(Xr,Xi,2,6,0.0f,sgn); BFX(Xr,Xi,3,7,-C7,sgn*C7);
  __syncthreads();
#pragma unroll
  for (int m = 0; m < 8; ++m) { int p = PADF(8*t + m); sre[p] = Xr[m]; sim[p] = Xi[m]; }
  __syncthreads();
  {
    int f0 = t & 7, f1 = t >> 3;
#pragma unroll
    for (int m = 0; m < 8; ++m) { int p = PADF(f0 + 8*m + 64*f1); Xr[m] = sre[p]; Xi[m] = sim[p]; }
    int x = 128*f0; float wr = twr[x], wi = sgn*twi[x];
    BFX(Xr,Xi,0,1,wr,wi); BFX(Xr,Xi,2,3,wr,wi); BFX(Xr,Xi,4,5,wr,wi); BFX(Xr,Xi,6,7,wr,wi);
    x = 64*f0;      float ar = twr[x], ai = sgn*twi[x];
    x = 64*(f0+8);  float br = twr[x], bi = sgn*twi[x];
    BFX(Xr,Xi,0,2,ar,ai); BFX(Xr,Xi,1,3,br,bi); BFX(Xr,Xi,4,6,ar,ai); BFX(Xr,Xi,5,7,br,bi);
#pragma unroll
    for (int mm = 0; mm < 4; ++mm) {
      x = 32*(f0 + 8*mm); float cr = twr[x], ci = sgn*twi[x];
      BFX(Xr,Xi,mm,mm+4,cr,ci);
    }
#pragma unroll
    for (int m = 0; m < 8; ++m) { int p = PADF(f0 + 8*m + 64*f1); sre[p] = Xr[m]; sim[p] = Xi[m]; }
  }
  __syncthreads();
  {
    int f0 = t & 63, f1 = t >> 6;
#pragma unroll
    for (int m = 0; m < 8; ++m) { int p = PADF(f0 + 64*m + 512*f1); Xr[m] = sre[p]; Xi[m] = sim[p]; }
    int x = 16*f0; float wr = twr[x], wi = sgn*twi[x];
    BFX(Xr,Xi,0,1,wr,wi); BFX(Xr,Xi,2,3,wr,wi); BFX(Xr,Xi,4,5,wr,wi); BFX(Xr,Xi,6,7,wr,wi);
    x = 8*f0;       float ar = twr[x], ai = sgn*twi[x];
    x = 8*(f0+64);  float br = twr[x], bi = sgn*twi[x];
    BFX(Xr,Xi,0,2,ar,ai); BFX(Xr,Xi,1,3,br,bi); BFX(Xr,Xi,4,6,ar,ai); BFX(Xr,Xi,5,7,br,bi);
#pragma unroll
    for (int mm = 0; mm < 4; ++mm) {
      x = 4*(f0 + 64*mm); float cr = twr[x], ci = sgn*twi[x];
      BFX(Xr,Xi,mm,mm+4,cr,ci);
    }
#pragma unroll
    for (int m = 0; m < 8; ++m) { int p = PADF(f0 + 64*m + 512*f1); sre[p] = Xr[m]; sim[p] = Xi[m]; }
  }
  __syncthreads();
  {
#pragma unroll
    for (int m = 0; m < 8; ++m) { int p = PADF(t + 128*m); Xr[m] = sre[p]; Xi[m] = sim[p]; }
#pragma unroll
    for (int mm = 0; mm < 4; ++mm) {
      int x = 2*t + 256*mm; float cr = twr[x], ci = sgn*twi[x];
      BFX(Xr,Xi,mm,mm+4,cr,ci);
    }
  }
}

// ---------------- DUAL register-ILP 1024-pt FFT: two frames per thread ----------------
// Same phases/barriers as fft1024, but each thread carries TWO independent frames
// (A in sreA/simA, B in sreB/simB). Doubles work between barriers (latency hiding),
// halves barriers/frame, reuses twiddle registers. Per-frame arithmetic identical.
__device__ __forceinline__ void fft1024_2(int t,
    float (&Ar)[8], float (&Ai)[8], float* __restrict__ sreA, float* __restrict__ simA,
    float (&Br)[8], float (&Bi)[8], float* __restrict__ sreB, float* __restrict__ simB,
    const float* __restrict__ twr, const float* __restrict__ twi, float sgn)
{
  const float C7 = 0.70710678118654752440f;
  BFX(Ar,Ai,0,1,1.0f,0.0f); BFX(Ar,Ai,2,3,1.0f,0.0f); BFX(Ar,Ai,4,5,1.0f,0.0f); BFX(Ar,Ai,6,7,1.0f,0.0f);
  BFX(Br,Bi,0,1,1.0f,0.0f); BFX(Br,Bi,2,3,1.0f,0.0f); BFX(Br,Bi,4,5,1.0f,0.0f); BFX(Br,Bi,6,7,1.0f,0.0f);
  BFX(Ar,Ai,0,2,1.0f,0.0f); BFX(Ar,Ai,1,3,0.0f,sgn); BFX(Ar,Ai,4,6,1.0f,0.0f); BFX(Ar,Ai,5,7,0.0f,sgn);
  BFX(Br,Bi,0,2,1.0f,0.0f); BFX(Br,Bi,1,3,0.0f,sgn); BFX(Br,Bi,4,6,1.0f,0.0f); BFX(Br,Bi,5,7,0.0f,sgn);
  BFX(Ar,Ai,0,4,1.0f,0.0f); BFX(Ar,Ai,1,5,C7,sgn*C7); BFX(Ar,Ai,2,6,0.0f,sgn); BFX(Ar,Ai,3,7,-C7,sgn*C7);
  BFX(Br,Bi,0,4,1.0f,0.0f); BFX(Br,Bi,1,5,C7,sgn*C7); BFX(Br,Bi,2,6,0.0f,sgn); BFX(Br,Bi,3,7,-C7,sgn*C7);
  __syncthreads();
#pragma unroll
  for (int m = 0; m < 8; ++m) {
    int p = PADF(8*t + m);
    sreA[p] = Ar[m]; simA[p] = Ai[m];
    sreB[p] = Br[m]; simB[p] = Bi[m];
  }
  __syncthreads();
  {
    int f0 = t & 7, f1 = t >> 3;
#pragma unroll
    for (int m = 0; m < 8; ++m) {
      int p = PADF(f0 + 8*m + 64*f1);
      Ar[m] = sreA[p]; Ai[m] = simA[p];
      Br[m] = sreB[p]; Bi[m] = simB[p];
    }
    int x = 128*f0; float wr = twr[x], wi = sgn*twi[x];
    BFX(Ar,Ai,0,1,wr,wi); BFX(Ar,Ai,2,3,wr,wi); BFX(Ar,Ai,4,5,wr,wi); BFX(Ar,Ai,6,7,wr,wi);
    BFX(Br,Bi,0,1,wr,wi); BFX(Br,Bi,2,3,wr,wi); BFX(Br,Bi,4,5,wr,wi); BFX(Br,Bi,6,7,wr,wi);
    x = 64*f0;      float ar = twr[x], ai = sgn*twi[x];
    x = 64*(f0+8);  float br = twr[x], bi = sgn*twi[x];
    BFX(Ar,Ai,0,2,ar,ai); BFX(Ar,Ai,1,3,br,bi); BFX(Ar,Ai,4,6,ar,ai); BFX(Ar,Ai,5,7,br,bi);
    BFX(Br,Bi,0,2,ar,ai); BFX(Br,Bi,1,3,br,bi); BFX(Br,Bi,4,6,ar,ai); BFX(Br,Bi,5,7,br,bi);
#pragma unroll
    for (int mm = 0; mm < 4; ++mm) {
      int x2 = 32*(f0 + 8*mm); float cr = twr[x2], ci = sgn*twi[x2];
      BFX(Ar,Ai,mm,mm+4,cr,ci);
      BFX(Br,Bi,mm,mm+4,cr,ci);
    }
#pragma unroll
    for (int m = 0; m < 8; ++m) {
      int p = PADF(f0 + 8*m + 64*f1);
      sreA[p] = Ar[m]; simA[p] = Ai[m];
      sreB[p] = Br[m]; simB[p] = Bi[m];
    }
  }
  __syncthreads();
  {
    int f0 = t & 63, f1 = t >> 6;
#pragma unroll
    for (int m = 0; m < 8; ++m) {
      int p = PADF(f0 + 64*m + 512*f1);
      Ar[m] = sreA[p]; Ai[m] = simA[p];
      Br[m] = sreB[p]; Bi[m] = simB[p];
    }
    int x = 16*f0; float wr = twr[x], wi = sgn*twi[x];
    BFX(Ar,Ai,0,1,wr,wi); BFX(Ar,Ai,2,3,wr,wi); BFX(Ar,Ai,4,5,wr,wi); BFX(Ar,Ai,6,7,wr,wi);
    BFX(Br,Bi,0,1,wr,wi); BFX(Br,Bi,2,3,wr,wi); BFX(Br,Bi,4,5,wr,wi); BFX(Br,Bi,6,7,wr,wi);
    x = 8*f0;       float ar = twr[x], ai = sgn*twi[x];
    x = 8*(f0+64);  float br = twr[x], bi = sgn*twi[x];
    BFX(Ar,Ai,0,2,ar,ai); BFX(Ar,Ai,1,3,br,bi); BFX(Ar,Ai,4,6,ar,ai); BFX(Ar,Ai,5,7,br,bi);
    BFX(Br,Bi,0,2,ar,ai); BFX(Br,Bi,1,3,br,bi); BFX(Br,Bi,4,6,ar,ai); BFX(Br,Bi,5,7,br,bi);
#pragma unroll
    for (int mm = 0; mm < 4; ++mm) {
      int x2 = 4*(f0 + 64*mm); float cr = twr[x2], ci = sgn*twi[x2];
      BFX(Ar,Ai,mm,mm+4,cr,ci);
      BFX(Br,Bi,mm,mm+4,cr,ci);
    }
#pragma unroll
    for (int m = 0; m < 8; ++m) {
      int p = PADF(f0 + 64*m + 512*f1);
      sreA[p] = Ar[m]; simA[p] = Ai[m];
      sreB[p] = Br[m]; simB[p] = Bi[m];
    }
  }
  __syncthreads();
  {
#pragma unroll
    for (int m = 0; m < 8; ++m) {
      int p = PADF(t + 128*m);
      Ar[m] = sreA[p]; Ai[m] = simA[p];
      Br[m] = sreB[p]; Bi[m] = simB[p];
    }
#pragma unroll
    for (int mm = 0; mm < 4; ++mm) {
      int x = 2*t + 256*mm; float cr = twr[x], ci = sgn*twi[x];
      BFX(Ar,Ai,mm,mm+4,cr,ci);
      BFX(Br,Bi,mm,mm+4,cr,ci);
    }
  }
}

// forward r2c epilogue (f32), single-frame
__device__ __forceinline__ void r2c_combine(int t, float (&Xr)[8], float (&Xi)[8],
    float* __restrict__ sre, float* __restrict__ sim,
    const float* __restrict__ twr, const float* __restrict__ twi,
    float& x1024r)
{
  __syncthreads();
#pragma unroll
  for (int m = 0; m < 8; ++m) { int p = PADF(t + 128*m); sre[p] = Xr[m]; sim[p] = Xi[m]; }
  __syncthreads();
  if (t == 0) x1024r = Xr[0] - Xi[0];
#pragma unroll
  for (int m = 0; m < 8; ++m) {
    int k  = t + 128*m;
    int km = PADF((1024 - k) & 1023);
    float zmr = sre[km], zmi = sim[km];
    float Er  = 0.5f*(Xr[m] + zmr), Ei  = 0.5f*(Xi[m] - zmi);
    float Odr = 0.5f*(Xr[m] - zmr), Odi = 0.5f*(Xi[m] + zmi);
    float Or  = Odi, Oi = -Odr;
    float wr  = twr[k], wi = -twi[k];
    Xr[m] = Er + (wr*Or - wi*Oi);
    Xi[m] = Ei + (wr*Oi + wi*Or);
  }
}

// forward r2c epilogue, dual-frame (shared barriers, per-frame math identical)
__device__ __forceinline__ void r2c_combine_2(int t,
    float (&Ar)[8], float (&Ai)[8], float* __restrict__ sreA, float* __restrict__ simA,
    float (&Br)[8], float (&Bi)[8], float* __restrict__ sreB, float* __restrict__ simB,
    const float* __restrict__ twr, const float* __restrict__ twi,
    float& x1024rA, float& x1024rB)
{
  __syncthreads();
#pragma unroll
  for (int m = 0; m < 8; ++m) {
    int p = PADF(t + 128*m);
    sreA[p] = Ar[m]; simA[p] = Ai[m];
    sreB[p] = Br[m]; simB[p] = Bi[m];
  }
  __syncthreads();
  if (t == 0) { x1024rA = Ar[0] - Ai[0]; x1024rB = Br[0] - Bi[0]; }
#pragma unroll
  for (int m = 0; m < 8; ++m) {
    int k  = t + 128*m;
    int km = PADF((1024 - k) & 1023);
    float wr  = twr[k], wi = -twi[k];
    {
      float zmr = sreA[km], zmi = simA[km];
      float Er  = 0.5f*(Ar[m] + zmr), Ei  = 0.5f*(Ai[m] - zmi);
      float Odr = 0.5f*(Ar[m] - zmr), Odi = 0.5f*(Ai[m] + zmi);
      float Or  = Odi, Oi = -Odr;
      Ar[m] = Er + (wr*Or - wi*Oi);
      Ai[m] = Ei + (wr*Oi + wi*Or);
    }
    {
      float zmr = sreB[km], zmi = simB[km];
      float Er  = 0.5f*(Br[m] + zmr), Ei  = 0.5f*(Bi[m] - zmi);
      float Odr = 0.5f*(Br[m] - zmr), Odi = 0.5f*(Bi[m] + zmi);
      float Or  = Odi, Oi = -Odr;
      Br[m] = Er + (wr*Or - wi*Oi);
      Bi[m] = Ei + (wr*Oi + wi*Or);
    }
  }
}

// mel -> linear interp for one bin k from LDS f32 melrow
__device__ inline float lin_interp_s(const float* __restrict__ melsh, int k) {
  float src = ((float)k + 0.5f) * ((float)NMELS / (float)NBINS) - 0.5f;
  src = src < 0.0f ? 0.0f : src;
  int i0 = (int)src; if (i0 > NMELS - 1) i0 = NMELS - 1;
  int i1 = i0 + 1 > NMELS - 1 ? NMELS - 1 : i0 + 1;
  float w = src - (float)i0;
  return (1.0f - w) * melsh[i0] + w * melsh[i1];
}

// ---------------- init A: paired window, win^2, f32 twiddles, f_pts, mel ranges ----------------
__global__ __launch_bounds__(256) void k_init_a(float2* __restrict__ winp,
                                                double* __restrict__ win2,
                                                float* __restrict__ twrf, float* __restrict__ twif,
                                                float* __restrict__ fptsf,
                                                int2* __restrict__ melrange) {
  int i = blockIdx.x * 256 + threadIdx.x;
  if (i < NFFT) {
    double w = 0.5 - 0.5 * cos(2.0 * M_PI * (double)i / (double)NFFT);
    win2[i] = w * w;
  }
  if (i < 1024) {
    double w0 = 0.5 - 0.5 * cos(2.0 * M_PI * (double)(2*i)   / (double)NFFT);
    double w1 = 0.5 - 0.5 * cos(2.0 * M_PI * (double)(2*i+1) / (double)NFFT);
    winp[i] = make_float2((float)w0, (float)w1);
    double th = 2.0 * M_PI * (double)i / (double)NFFT;
    twrf[i] = (float)cos(th); twif[i] = (float)sin(th);
  }
  if (i < NMELS + 2) {                   // f_pts[82], same formula/order as reference
    double m_max = 2595.0 * log10(1.0 + (SRATE / 2.0) / 700.0);
    fptsf[i] = (float)(700.0 * (pow(10.0, ((double)i * m_max / (double)(NMELS + 1)) / 2595.0) - 1.0));
  }
  if (i < NMELS) {                       // per-mel positive-weight bin range [lo,hi) — analytic
    double m_max = 2595.0 * log10(1.0 + (SRATE / 2.0) / 700.0);
    double fp0 = 700.0 * (pow(10.0, ((double)i       * m_max / (double)(NMELS + 1)) / 2595.0) - 1.0);
    double fp1 = 700.0 * (pow(10.0, ((double)(i + 1) * m_max / (double)(NMELS + 1)) / 2595.0) - 1.0);
    double fp2 = 700.0 * (pow(10.0, ((double)(i + 2) * m_max / (double)(NMELS + 1)) / 2595.0) - 1.0);
    int lo = (int)floor(fp0 / 7.8125) + 1;
    int hi = (int)ceil (fp2 / 7.8125);
    if (lo < 0) lo = 0; if (lo > NBINS) lo = NBINS;
    if (hi < 0) hi = 0; if (hi > NBINS) hi = NBINS;
    #define WGT(k) fmin(((double)(k)*7.8125 - fp0)/(fp1 - fp0), (fp2 - (double)(k)*7.8125)/(fp2 - fp1))
    while (lo > 0 && WGT(lo - 1) > 0.0) --lo;
    while (lo < hi && WGT(lo) <= 0.0) ++lo;
    while (hi < NBINS && WGT(hi) > 0.0) ++hi;
    while (hi > lo && WGT(hi - 1) <= 0.0) --hi;
    #undef WGT
    melrange[i] = make_int2(lo, hi);
  }
}

// ---------------- init B: envelope reciprocal ----------------
__global__ __launch_bounds__(256) void k_init_b(const double* __restrict__ win2,
                                                float* __restrict__ envif) {
  int i = blockIdx.x * 256 + threadIdx.x;
  if (i < LOLA) {
    int lo = i - (NFFT - 1);
    int fmin = lo <= 0 ? 0 : (lo + HOP - 1) / HOP;
    int fmax = i / HOP; if (fmax > NF - 1) fmax = NF - 1;
    double s = 0.0;
    for (int f = fmin; f <= fmax; ++f) s += win2[i - HOP * f];
    envif[i] = (float)(1.0 / (s > 1e-11 ? s : 1.0));
  }
}

// ---------------- STFT (real-packed, f32) + mel GATHER (no atomics) ----------------
__global__ __launch_bounds__(128) void k_stft_mel(const float* __restrict__ x,
                                                  const float2* __restrict__ winp,
                                                  const float* __restrict__ twrf, const float* __restrict__ twif,
                                                  const float* __restrict__ fptsf, const int2* __restrict__ melrange,
                                                  float* __restrict__ mel) {
  __shared__ float sre[1160], sim[1160];
  __shared__ float fsh[NMELS + 2];
  __shared__ int2  rsh[NMELS];
  int b = blockIdx.x / NF, tf = blockIdx.x % NF;
  int t = threadIdx.x;
  const float* xb = x + (size_t)b * TLEN;
  if (t < NMELS + 2) fsh[t] = fptsf[t];
  if (t < NMELS)     rsh[t] = melrange[t];
  if (tf >= 4 && tf <= 508) {            // interior: natural float2 loads
    const float2* xb2 = (const float2*)xb;
#pragma unroll
    for (int s = 0; s < 8; ++s) {
      int n = t + 128 * s;
      float2 v = xb2[128 * tf + n - 512];
      float2 w = winp[n];
      sre[PADF(n)] = v.x * w.x;
      sim[PADF(n)] = v.y * w.y;
    }
  } else {
#pragma unroll
    for (int s = 0; s < 8; ++s) {        // boundary: reflect scalar path
      int n = t + 128 * s;
      int j0 = HOP * tf + 2 * n - (NFFT / 2);
      int m0 = j0 < 0 ? -j0 : (j0 >= TLEN ? 2 * TLEN - 2 - j0 : j0);
      int j1 = j0 + 1;
      int m1 = j1 < 0 ? -j1 : (j1 >= TLEN ? 2 * TLEN - 2 - j1 : j1);
      float2 w = winp[n];
      sre[PADF(n)] = xb[m0] * w.x;
      sim[PADF(n)] = xb[m1] * w.y;
    }
  }
  __syncthreads();
  float Xr[8], Xi[8];
  int rt = (int)(__brev((unsigned)t) >> 25);
  const int r3[8] = {0,4,2,6,1,5,3,7};
#pragma unroll
  for (int m = 0; m < 8; ++m) {
    int p = PADF(rt + 128 * r3[m]);
    Xr[m] = sre[p]; Xi[m] = sim[p];
  }
  fft1024(t, Xr, Xi, sre, sim, twrf, twif, -1.0f);
  float x1024r = 0.0f;
  r2c_combine(t, Xr, Xi, sre, sim, twrf, twif, x1024r);
  __syncthreads();
#pragma unroll
  for (int m = 0; m < 8; ++m) {
    int k = t + 128 * m;
    sre[k] = sqrtf(Xr[m]*Xr[m] + Xi[m]*Xi[m]);
  }
  if (t == 0) sre[1024] = fabsf(x1024r);
  __syncthreads();
  if (t < NMELS) {                        // gather: one mel per thread
    float fp0 = fsh[t], fp1 = fsh[t + 1], fp2 = fsh[t + 2];
    float id0 = 1.0f / (fp1 - fp0), id1 = 1.0f / (fp2 - fp1);
    int2 r = rsh[t];
    float acc = 0.0f;
    for (int k = r.x; k < r.y; ++k) {
      float freq = (float)k * DF;
      float w = fminf((freq - fp0) * id0, (fp2 - freq) * id1);
      acc += sre[k] * fmaxf(w, 0.0f);
    }
    mel[(size_t)blockIdx.x * NMELS + t] = acc;
  }
}

// ---------------- iSTFT #0, register-dual: threefry angles fused, 2 frames/thread -------------
// 128 threads; frames r0=2*bid, r1=2*bid+1 both carried in each thread's registers.
// Doubles per-thread ILP between barriers (the diagnosed stall), barrier count per
// frame halves. Per-frame values bit-identical to the single-frame version.
__global__ __launch_bounds__(128) void k_istft0(const float* __restrict__ mel,
                                                const float2* __restrict__ winp,
                                                const float* __restrict__ twrf, const float* __restrict__ twif,
                                                float2* __restrict__ fr2,
                                                uint32_t kr0, uint32_t kr1,
                                                uint32_t ki0, uint32_t ki1) {
  __shared__ float sreA[1160], simA[1160], sreB[1160], simB[1160];
  __shared__ float melshA[NMELS], melshB[NMELS];
  int t = threadIdx.x;
  size_t r0 = (size_t)blockIdx.x * 2, r1 = r0 + 1;
  int b0 = (int)(r0 / NF), tf0 = (int)(r0 % NF);
  int b1 = (int)(r1 / NF), tf1 = (int)(r1 % NF);
  if (t < NMELS) { melshA[t] = mel[r0 * NMELS + t]; melshB[t] = mel[r1 * NMELS + t]; }
  __syncthreads();
  for (int s = 0; s < 9; ++s) {          // stage X[k] = spec*angle for both frames
    int k = t + 128 * s;
    if (k < NBINS) {
      uint32_t a0, a1, b0w, b1w;
      uint32_t jA = ((uint32_t)b0 * (uint32_t)NBINS + (uint32_t)k) * (uint32_t)NF + (uint32_t)tf0;
      threefry2x32(kr0, kr1, 0u, jA, a0, a1);
      threefry2x32(ki0, ki1, 0u, jA, b0w, b1w);
      float svA = lin_interp_s(melshA, k);
      sreA[PADF(k)] = svA * bits_to_uniform(a0 ^ a1);
      simA[PADF(k)] = (k == 0 || k == 1024) ? 0.0f : svA * bits_to_uniform(b0w ^ b1w);
      uint32_t jB = ((uint32_t)b1 * (uint32_t)NBINS + (uint32_t)k) * (uint32_t)NF + (uint32_t)tf1;
      threefry2x32(kr0, kr1, 0u, jB, a0, a1);
      threefry2x32(ki0, ki1, 0u, jB, b0w, b1w);
      float svB = lin_interp_s(melshB, k);
      sreB[PADF(k)] = svB * bits_to_uniform(a0 ^ a1);
      simB[PADF(k)] = (k == 0 || k == 1024) ? 0.0f : svB * bits_to_uniform(b0w ^ b1w);
    }
  }
  __syncthreads();
  float Ar[8], Ai[8], Br[8], Bi[8];
  int rt = (int)(__brev((unsigned)t) >> 25);
  const int r3[8] = {0,4,2,6,1,5,3,7};
#pragma unroll
  for (int m = 0; m < 8; ++m) {          // Z[n] = E + i*O, gathered bit-reversed (both)
    int n  = rt + 128 * r3[m];
    int p  = PADF(n), q = PADF(1024 - n);
    float wr = twrf[n], wi = twif[n];
    {
      float Er = 0.5f*(sreA[p] + sreA[q]), Ei = 0.5f*(simA[p] - simA[q]);
      float Fr = 0.5f*(sreA[p] - sreA[q]), Fi = 0.5f*(simA[p] + simA[q]);
      float Or = wr*Fr - wi*Fi, Oi = wr*Fi + wi*Fr;
      Ar[m] = Er - Oi;  Ai[m] = Ei + Or;
    }
    {
      float Er = 0.5f*(sreB[p] + sreB[q]), Ei = 0.5f*(simB[p] - simB[q]);
      float Fr = 0.5f*(sreB[p] - sreB[q]), Fi = 0.5f*(simB[p] + simB[q]);
      float Or = wr*Fr - wi*Fi, Oi = wr*Fi + wi*Fr;
      Br[m] = Er - Oi;  Bi[m] = Ei + Or;
    }
  }
  fft1024_2(t, Ar, Ai, sreA, simA, Br, Bi, sreB, simB, twrf, twif, +1.0f);
  float2* frA = fr2 + r0 * 1024;
  float2* frB = fr2 + r1 * 1024;
  const float invM = 1.0f / 1024.0f;
#pragma unroll
  for (int m = 0; m < 8; ++m) {
    int g = t + 128 * m;
    float2 w = winp[g];
    frA[g] = make_float2(Ar[m] * invM * w.x, Ai[m] * invM * w.y);
    frB[g] = make_float2(Br[m] * invM * w.x, Bi[m] * invM * w.y);
  }
}

// ---------------- FUSED register-dual: STFT(y) + GL update + iSTFT, 2 frames/thread ----------
__global__ __launch_bounds__(128) void k_gl_istft(const float* __restrict__ y,
                                                  const float* __restrict__ mel,
                                                  const float2* __restrict__ winp,
                                                  const float* __restrict__ twrf, const float* __restrict__ twif,
                                                  float2* __restrict__ P, float2* __restrict__ fr2,
                                                  float momf, int writeP) {
  __shared__ float sreA[1160], simA[1160], sreB[1160], simB[1160];
  __shared__ float melshA[NMELS], melshB[NMELS];
  int t = threadIdx.x;
  size_t r0 = (size_t)blockIdx.x * 2, r1 = r0 + 1;
  int b0 = (int)(r0 / NF), tf0 = (int)(r0 % NF);
  int b1 = (int)(r1 / NF), tf1 = (int)(r1 % NF);
  float2* ProwA = P + r0 * NBINS;
  float2* ProwB = P + r1 * NBINS;
  const bool readP = (momf != 0.0f);
  float2 pfrA[8], pfrB[8];
  float2 pnyA = make_float2(0.0f, 0.0f), pnyB = make_float2(0.0f, 0.0f);
  if (readP) {                           // prefetch both momentum rows under the FFT
#pragma unroll
    for (int m = 0; m < 8; ++m) { pfrA[m] = ProwA[t + 128 * m]; pfrB[m] = ProwB[t + 128 * m]; }
    if (t == 0) { pnyA = ProwA[1024]; pnyB = ProwB[1024]; }
  } else {
#pragma unroll
    for (int m = 0; m < 8; ++m) { pfrA[m] = make_float2(0.f,0.f); pfrB[m] = make_float2(0.f,0.f); }
  }
  if (t < NMELS) { melshA[t] = mel[r0 * NMELS + t]; melshB[t] = mel[r1 * NMELS + t]; }
  // stage frame A
  {
    const float* yb = y + (size_t)b0 * LOLA;
    if (tf0 >= 4 && tf0 <= 508) {
      const float2* yb2 = (const float2*)yb;
#pragma unroll
      for (int s = 0; s < 8; ++s) {
        int n = t + 128 * s;
        float2 v = yb2[128 * tf0 + n];
        float2 w = winp[n];
        sreA[PADF(n)] = v.x * w.x;
        simA[PADF(n)] = v.y * w.y;
      }
    } else {
#pragma unroll
      for (int s = 0; s < 8; ++s) {
        int n = t + 128 * s;
        int j0 = HOP * tf0 + 2 * n - (NFFT / 2);
        int m0 = j0 < 0 ? -j0 : (j0 >= TLEN ? 2 * TLEN - 2 - j0 : j0);
        int j1 = j0 + 1;
        int m1 = j1 < 0 ? -j1 : (j1 >= TLEN ? 2 * TLEN - 2 - j1 : j1);
        float2 w = winp[n];
        sreA[PADF(n)] = yb[NFFT/2 + m0] * w.x;
        simA[PADF(n)] = yb[NFFT/2 + m1] * w.y;
      }
    }
  }
  // stage frame B
  {
    const float* yb = y + (size_t)b1 * LOLA;
    if (tf1 >= 4 && tf1 <= 508) {
      const float2* yb2 = (const float2*)yb;
#pragma unroll
      for (int s = 0; s < 8; ++s) {
        int n = t + 128 * s;
        float2 v = yb2[128 * tf1 + n];
        float2 w = winp[n];
        sreB[PADF(n)] = v.x * w.x;
        simB[PADF(n)] = v.y * w.y;
      }
    } else {
#pragma unroll
      for (int s = 0; s < 8; ++s) {
        int n = t + 128 * s;
        int j0 = HOP * tf1 + 2 * n - (NFFT / 2);
        int m0 = j0 < 0 ? -j0 : (j0 >= TLEN ? 2 * TLEN - 2 - j0 : j0);
        int j1 = j0 + 1;
        int m1 = j1 < 0 ? -j1 : (j1 >= TLEN ? 2 * TLEN - 2 - j1 : j1);
        float2 w = winp[n];
        sreB[PADF(n)] = yb[NFFT/2 + m0] * w.x;
        simB[PADF(n)] = yb[NFFT/2 + m1] * w.y;
      }
    }
  }
  __syncthreads();
  float Ar[8], Ai[8], Br[8], Bi[8];
  int rt = (int)(__brev((unsigned)t) >> 25);
  const int r3[8] = {0,4,2,6,1,5,3,7};
#pragma unroll
  for (int m = 0; m < 8; ++m) {
    int p = PADF(rt + 128 * r3[m]);
    Ar[m] = sreA[p]; Ai[m] = simA[p];
    Br[m] = sreB[p]; Bi[m] = simB[p];
  }
  fft1024_2(t, Ar, Ai, sreA, simA, Br, Bi, sreB, simB, twrf, twif, -1.0f);
  float x1024rA = 0.0f, x1024rB = 0.0f;
  r2c_combine_2(t, Ar, Ai, sreA, simA, Br, Bi, sreB, simB, twrf, twif, x1024rA, x1024rB);
  __syncthreads();                       // all r2c reads done before spec overwrite
#pragma unroll
  for (int m = 0; m < 8; ++m) {          // GL angle + momentum for both frames
    int k = t + 128 * m;
    {
      float ar = Ar[m] - momf * pfrA[m].x;
      float ai = Ai[m] - momf * pfrA[m].y;
      float mg = sqrtf(ar * ar + ai * ai) + 1e-16f;
      float inv = 1.0f / mg;
      if (writeP) ProwA[k] = make_float2(Ar[m], Ai[m]);
      float sv = lin_interp_s(melshA, k);
      sreA[PADF(k)] = sv * (ar * inv);
      simA[PADF(k)] = (k == 0) ? 0.0f : sv * (ai * inv);
    }
    {
      float ar = Br[m] - momf * pfrB[m].x;
      float ai = Bi[m] - momf * pfrB[m].y;
      float mg = sqrtf(ar * ar + ai * ai) + 1e-16f;
      float inv = 1.0f / mg;
      if (writeP) ProwB[k] = make_float2(Br[m], Bi[m]);
      float sv = lin_interp_s(melshB, k);
      sreB[PADF(k)] = sv * (ar * inv);
      simB[PADF(k)] = (k == 0) ? 0.0f : sv * (ai * inv);
    }
  }
  if (t == 0) {                          // Nyquist bins
    {
      float ar = x1024rA - momf * pnyA.x;
      float ai = -momf * pnyA.y;
      float mg = sqrtf(ar * ar + ai * ai) + 1e-16f;
      float inv = 1.0f / mg;
      if (writeP) ProwA[1024] = make_float2(x1024rA, 0.0f);
      float sv = lin_interp_s(melshA, 1024);
      sreA[PADF(1024)] = sv * (ar * inv);
      simA[PADF(1024)] = 0.0f;
      (void)ai;
    }
    {
      float ar = x1024rB - momf * pnyB.x;
      float ai = -momf * pnyB.y;
      float mg = sqrtf(ar * ar + ai * ai) + 1e-16f;
      float inv = 1.0f / mg;
      if (writeP) ProwB[1024] = make_float2(x1024rB, 0.0f);
      float sv = lin_interp_s(melshB, 1024);
      sreB[PADF(1024)] = sv * (ar * inv);
      simB[PADF(1024)] = 0.0f;
      (void)ai;
    }
  }
  __syncthreads();
#pragma unroll
  for (int m = 0; m < 8; ++m) {          // c2r staging for both frames
    int n  = rt + 128 * r3[m];
    int p  = PADF(n), q = PADF(1024 - n);
    float wr = twrf[n], wi = twif[n];
    {
      float Er = 0.5f*(sreA[p] + sreA[q]), Ei = 0.5f*(simA[p] - simA[q]);
      float Fr = 0.5f*(sreA[p] - sreA[q]), Fi = 0.5f*(simA[p] + simA[q]);
      float Or = wr*Fr - wi*Fi, Oi = wr*Fi + wi*Fr;
      Ar[m] = Er - Oi;  Ai[m] = Ei + Or;
    }
    {
      float Er = 0.5f*(sreB[p] + sreB[q]), Ei = 0.5f*(simB[p] - simB[q]);
      float Fr = 0.5f*(sreB[p] - sreB[q]), Fi = 0.5f*(simB[p] + simB[q]);
      float Or = wr*Fr - wi*Fi, Oi = wr*Fi + wi*Fr;
      Br[m] = Er - Oi;  Bi[m] = Ei + Or;
    }
  }
  fft1024_2(t, Ar, Ai, sreA, simA, Br, Bi, sreB, simB, twrf, twif, +1.0f);
  float2* frA = fr2 + r0 * 1024;
  float2* frB = fr2 + r1 * 1024;
  const float invM = 1.0f / 1024.0f;
#pragma unroll
  for (int m = 0; m < 8; ++m) {
    int g = t + 128 * m;
    float2 w = winp[g];
    frA[g] = make_float2(Ar[m] * invM * w.x, Ai[m] * invM * w.y);
    frB[g] = make_float2(Br[m] * invM * w.x, Bi[m] * invM * w.y);
  }
}

// ---------------- OLA gather + normalize, 4 samples/thread ----------------
__global__ __launch_bounds__(256) void k_ola(const float* __restrict__ fr,
                                             const float* __restrict__ envif,
                                             float* __restrict__ y, float* __restrict__ out) {
  size_t idx = (size_t)blockIdx.x * 256 + threadIdx.x;
  const size_t QROW = LOLA / 4;           // 33280 quads per batch row
  if (idx >= (size_t)BATCH * QROW) return;
  int b = (int)(idx / QROW);
  int i0 = 4 * (int)(idx % QROW);
  const float* frb = fr + (size_t)b * NF * NFFT;
  int lo0 = i0 - (NFFT - 1);
  int fm0 = lo0 <= 0 ? 0 : (lo0 + HOP - 1) / HOP;
  int fx0 = i0 / HOP; if (fx0 > NF - 1) fx0 = NF - 1;
  int i3 = i0 + 3;
  int lo3 = i3 - (NFFT - 1);
  int fm3 = lo3 <= 0 ? 0 : (lo3 + HOP - 1) / HOP;
  int fx3 = i3 / HOP; if (fx3 > NF - 1) fx3 = NF - 1;
  float4 v;
  if (fm0 == fm3 && fx0 == fx3) {         // uniform range: float4 fast path
    float4 s = make_float4(0.f, 0.f, 0.f, 0.f);
    for (int f = fm0; f <= fx0; ++f) {
      const float4 a = *(const float4*)(frb + (size_t)f * NFFT + (i0 - HOP * f));
      s.x += a.x; s.y += a.y; s.z += a.z; s.w += a.w;
    }
    const float4 e = *(const float4*)(envif + i0);
    v = make_float4(s.x * e.x, s.y * e.y, s.z * e.z, s.w * e.w);
  } else {                                // boundary quad: per-element
    float vv[4];
#pragma unroll
    for (int u = 0; u < 4; ++u) {
      int i = i0 + u;
      int lo = i - (NFFT - 1);
      int fmin = lo <= 0 ? 0 : (lo + HOP - 1) / HOP;
      int fmax = i / HOP; if (fmax > NF - 1) fmax = NF - 1;
      float s = 0.0f;
      for (int f = fmin; f <= fmax; ++f)
        s += frb[(size_t)f * NFFT + (i - HOP * f)];
      vv[u] = s * envif[i];
    }
    v = make_float4(vv[0], vv[1], vv[2], vv[3]);
  }
  if (out) {
    int j0 = i0 - NFFT / 2;               // 1024-aligned shift: j0 % 4 == 0
    if (j0 >= 0 && j0 + 3 < TLEN) {
      *(float4*)(out + (size_t)b * TLEN + j0) = v;
    } else {
      const float vv[4] = {v.x, v.y, v.z, v.w};
#pragma unroll
      for (int u = 0; u < 4; ++u) {
        int j = j0 + u;
        if (j >= 0 && j < TLEN) out[(size_t)b * TLEN + j] = vv[u];
      }
    }
  } else {
    *(float4*)(y + (size_t)b * LOLA + i0) = v;
  }
}

// ---------------- f0 + loudness (constant-sum lag quads, 8 n-phases) ----------------
// Round-3-proven version (72.4us). LDS padding experiments all regressed — keeping.
__global__ __launch_bounds__(256) void k_feats(const float* __restrict__ x, double* __restrict__ feats) {
  __shared__ __align__(16) double xd[528];   // frame in f64; [512..527] zero pad
  __shared__ double pacc[8][224];            // per-phase lag partials
  __shared__ double red[256];                // loudness reduce
  __shared__ double cval[256];
  __shared__ int    cidx[256];
  int b = blockIdx.x / NF, tf = blockIdx.x % NF;
  const float* xb = x + (size_t)b * TLEN;
  int tid = threadIdx.x;
  for (int n = tid; n < FRAMEL; n += 256) {
    int j = HOP * tf + n - (FRAMEL / 2);
    int m = j < 0 ? -j : (j >= TLEN ? 2 * TLEN - 2 - j : j);
    xd[n] = (double)xb[m];
  }
  if (tid < 16) xd[FRAMEL + tid] = 0.0;
  __syncthreads();
  double ss = 0.0;
  for (int n = tid; n < FRAMEL; n += 256) { double v = xd[n]; ss += v * v; }
  red[tid] = ss;
  __syncthreads();
  for (int w = 128; w > 0; w >>= 1) {
    if (tid < w) red[tid] += red[tid + w];
    __syncthreads();
  }
  double sumsq = red[0];
  int g = tid & 31, ph = tid >> 5;
  double acc[8];
#pragma unroll
  for (int d = 0; d < 8; ++d) acc[d] = 0.0;
  if (g < 28) {
    const double2* d2 = (const double2*)xd;
    const int LA = 32 + 4 * g;            // quad A: lags LA..LA+3 (32..143)
    const int LB = 252 - 4 * g;           // quad B: lags LB..LB+3 (144..255)
    for (int n0 = 8 * ph; n0 < 512 - LA; n0 += 64) {
      int h = n0 >> 1, hb = (n0 + LA) >> 1;
      double2 a0 = d2[h],      a1 = d2[h + 1],  a2 = d2[h + 2],  a3 = d2[h + 3];
      double2 b0 = d2[hb],     b1 = d2[hb + 1], b2 = d2[hb + 2],
              b3 = d2[hb + 3], b4 = d2[hb + 4], b5 = d2[hb + 5];
      double aa[8]  = {a0.x,a0.y,a1.x,a1.y,a2.x,a2.y,a3.x,a3.y};
      double bb[12] = {b0.x,b0.y,b1.x,b1.y,b2.x,b2.y,b3.x,b3.y,b4.x,b4.y,b5.x,b5.y};
#pragma unroll
      for (int d = 0; d < 4; ++d)
#pragma unroll
        for (int jj = 0; jj < 8; ++jj)
          acc[d] += aa[jj] * bb[jj + d];
    }
    for (int n0 = 8 * ph; n0 < 512 - LB; n0 += 64) {
      int h = n0 >> 1, hb = (n0 + LB) >> 1;
      double2 a0 = d2[h],      a1 = d2[h + 1],  a2 = d2[h + 2],  a3 = d2[h + 3];
      double2 b0 = d2[hb],     b1 = d2[hb + 1], b2 = d2[hb + 2],
              b3 = d2[hb + 3], b4 = d2[hb + 4], b5 = d2[hb + 5];
      double aa[8]  = {a0.x,a0.y,a1.x,a1.y,a2.x,a2.y,a3.x,a3.y};
      double bb[12] = {b0.x,b0.y,b1.x,b1.y,b2.x,b2.y,b3.x,b3.y,b4.x,b4.y,b5.x,b5.y};
#pragma unroll
      for (int d = 0; d < 4; ++d)
#pragma unroll
        for (int jj = 0; jj < 8; ++jj)
          acc[4 + d] += aa[jj] * bb[jj + d];
    }
#pragma unroll
    for (int d = 0; d < 8; ++d) pacc[ph][g * 8 + d] = acc[d];
  }
  __syncthreads();
  if (tid < 224) {
    double tot = 0.0;
#pragma unroll
    for (int p = 0; p < 8; ++p) tot += pacc[p][tid];
    int gg = tid >> 3, dd = tid & 7;
    int lag = dd < 4 ? (32 + 4 * gg + dd) : (252 - 4 * gg + (dd - 4));
    cval[tid] = tot; cidx[tid] = lag;
  } else { cval[tid] = -1e300; cidx[tid] = 1 << 30; }
  __syncthreads();
  for (int w = 128; w > 0; w >>= 1) {
    if (tid < w) {
      double vl = cval[tid], vr = cval[tid + w];
      int il = cidx[tid], ir = cidx[tid + w];
      if (vr > vl || (vr == vl && ir < il)) { cval[tid] = vr; cidx[tid] = ir; }
    }
    __syncthreads();
  }
  if (tid == 0) {
    double period = (double)cidx[0];
    double f0 = (double)SRATE / (period + 1e-8);
    f0 = f0 < 50.0 ? 50.0 : (f0 > 500.0 ? 500.0 : f0);
    double mean = sumsq / (double)FRAMEL;
    double loud = 20.0 * log10(sqrt(mean) + 1e-8);
    feats[(size_t)blockIdx.x * 2 + 0] = f0;
    feats[(size_t)blockIdx.x * 2 + 1] = loud;
  }
}

// ---------------- MLP 2->256->256->64 (elu), f32, 4 rows/block ----------------
__global__ __launch_bounds__(256) void k_mlp(const double* __restrict__ feats,
                                             const float* __restrict__ W1, const float* __restrict__ b1,
                                             const float* __restrict__ W2, const float* __restrict__ b2,
                                             const float* __restrict__ W3, const float* __restrict__ b3,
                                             float* __restrict__ out) {
  __shared__ __align__(16) float h1[MLPR][256];
  __shared__ __align__(16) float h2[MLPR][256];
  __shared__ float fsh[MLPR][2];
  int j = threadIdx.x;
  size_t row0 = (size_t)blockIdx.x * MLPR;
  if (j < MLPR * 2) ((float*)fsh)[j] = (float)feats[row0 * 2 + j];
  __syncthreads();
  float w1a = W1[j], w1b = W1[256 + j], bb1 = b1[j];
#pragma unroll
  for (int r = 0; r < MLPR; ++r) {
    float v = fsh[r][0] * w1a + fsh[r][1] * w1b + bb1;
    h1[r][j] = v > 0.0f ? v : expm1f(v);
  }
  __syncthreads();
  float acc[MLPR];
  float bb2 = b2[j];
#pragma unroll
  for (int r = 0; r < MLPR; ++r) acc[r] = bb2;
  const float* w2p = W2 + j;
  for (int i4 = 0; i4 < 64; ++i4) {
    float w0 = w2p[(4 * i4 + 0) * 256];
    float w1 = w2p[(4 * i4 + 1) * 256];
    float w2v = w2p[(4 * i4 + 2) * 256];
    float w3v = w2p[(4 * i4 + 3) * 256];
#pragma unroll
    for (int r = 0; r < MLPR; ++r) {
      float4 hv = ((const float4*)h1[r])[i4];   // broadcast read
      acc[r] += hv.x * w0;
      acc[r] += hv.y * w1;
      acc[r] += hv.z * w2v;
      acc[r] += hv.w * w3v;
    }
  }
#pragma unroll
  for (int r = 0; r < MLPR; ++r) h2[r][j] = acc[r] > 0.0f ? acc[r] : expm1f(acc[r]);
  __syncthreads();
  int o = j & 63, r = j >> 6;             // one row per 64-lane wave (wave-uniform r)
  float oacc = b3[o];
  const float* w3p = W3 + o;
  for (int i4 = 0; i4 < 64; ++i4) {
    float4 hv = ((const float4*)h2[r])[i4];     // broadcast read
    oacc += hv.x * w3p[(4 * i4 + 0) * 64];
    oacc += hv.y * w3p[(4 * i4 + 1) * 64];
    oacc += hv.z * w3p[(4 * i4 + 2) * 64];
    oacc += hv.w * w3p[(4 * i4 + 3) * 64];
  }
  out[(row0 + r) * 64 + o] = oacc;
}

// sentinel: marks "workspace too small" path unambiguously
__global__ void k_sentinel(float* out) { out[0] = 31337.0f; }

// ---------------- host ----------------
extern "C" void kernel_launch(void* const* d_in, const int* in_sizes, int n_in,
                              void* d_out, int out_size, void* d_ws, size_t ws_size,
                              hipStream_t stream) {
  const float* x  = (const float*)d_in[0];
  const float* W1 = (const float*)d_in[1];
  const float* b1 = (const float*)d_in[2];
  const float* W2 = (const float*)d_in[3];
  const float* b2 = (const float*)d_in[4];
  const float* W3 = (const float*)d_in[5];
  const float* b3 = (const float*)d_in[6];
  float* out = (float*)d_out;

  // f64 region
  double* ws = (double*)d_ws;
  size_t o = 0;
  double*  winsq = ws + o; o += NFFT;
  double*  feats = ws + o; o += (size_t)BATCH * NF * 2;
  // f32 region (8B aligned: o doubles consumed)
  float2* winp  = (float2*)(ws + o);                         // 1024 float2
  float*  twrf  = (float*)(winp + 1024);                     // 1024
  float*  twif  = twrf + 1024;                               // 1024
  float*  fptsf = twif + 1024;                               // 84 (pad to even)
  int2*   melrange = (int2*)(fptsf + 84);                    // 80 int2 (8B aligned)
  float*  mel   = (float*)(melrange + NMELS);                // B*NF*80
  float*  fr    = mel + (size_t)BATCH * NF * NMELS;          // B*NF*2048 windowed frames
  float*  y     = fr + (size_t)BATCH * NF * NFFT;            // B*LOLA normalized inv
  float*  envif = y + (size_t)BATCH * LOLA;                  // LOLA
  float2* P     = (float2*)(envif + LOLA);                   // momentum (A is never materialized)
  size_t total_bytes = (size_t)((char*)(P + (size_t)NELEM) - (char*)d_ws);  // ~148 MiB

  if (ws_size < total_bytes) {           // diagnostic path: out[0] = 31337
    k_sentinel<<<1, 1, 0, stream>>>(out);
    return;
  }

  // jax.random.key(42) -> (0,42). Partitionable split: keys[i] = threefry(key, (0, i)).
  uint32_t kr0, kr1, ki0, ki1;
  threefry2x32(0u, 42u, 0u, 0u, kr0, kr1);   // kr = keys[0]
  threefry2x32(0u, 42u, 0u, 1u, ki0, ki1);   // ki = keys[1]

  const int NBLK = BATCH * NF;    // 8208
  const int OLAB = ((size_t)BATCH * (LOLA / 4) + 255) / 256;   // 4 samples/thread
  k_init_a<<<8, 256, 0, stream>>>(winp, winsq, twrf, twif, fptsf, melrange);
  k_init_b<<<(LOLA + 255) / 256, 256, 0, stream>>>(winsq, envif);
  k_stft_mel<<<NBLK, 128, 0, stream>>>(x, winp, twrf, twif, fptsf, melrange, mel);

  const float momf = (float)(0.99 / 1.99);   // reference: f32 multiply of python-f64 scalar
  // istft #0 with fused threefry angles; register-dual: 2 frames per 128-thread block
  k_istft0<<<NBLK / 2, 128, 0, stream>>>(mel, winp, twrf, twif, (float2*)fr, kr0, kr1, ki0, ki1);
  k_ola<<<OLAB, 256, 0, stream>>>(fr, envif, y, nullptr);
  for (int it = 0; it < 4; ++it) {
    // fused register-dual: STFT(y) -> GL angle update -> iSTFT -> fr.
    // it==0: mom=0 (P unread). it==3: final angles, P dead -> writeP=0.
    k_gl_istft<<<NBLK / 2, 128, 0, stream>>>(y, mel, winp, twrf, twif, P, (float2*)fr,
                                             it == 0 ? 0.0f : momf, it < 3 ? 1 : 0);
    k_ola<<<OLAB, 256, 0, stream>>>(fr, envif, y, it == 3 ? out : nullptr);
  }

  k_feats<<<NBLK, 256, 0, stream>>>(x, feats);
  k_mlp<<<NBLK / MLPR, 256, 0, stream>>>(feats, W1, b1, W2, b2, W3, b3, out + (size_t)BATCH * TLEN);
}